// Round 9
// baseline (348.353 us; speedup 1.0000x reference)
//
#include <hip/hip_runtime.h>
#include <hip/hip_bf16.h>

#define N_NODES 50000
#define N_EDGES 800000
#define F 128
#define L 64
#define BN_EPS 1e-5f
#define SCAN_BLOCKS 196   // ceil(50000/256)
#define BN_BLOCKS 391     // ceil(50000/128)
#define NPART 8
#define PART_SZ 6250      // 50000/8

typedef __attribute__((ext_vector_type(8))) short short8;
typedef __attribute__((ext_vector_type(8))) unsigned short ushort8;
typedef __attribute__((ext_vector_type(4))) float f32x4;

// ---------------- runtime dtype adaptivity ----------------
// flags[0] = 1 if float inputs are fp32, 0 if bf16
// flags[1] = 1 if edge_index is int64, 0 if int32
static __device__ __forceinline__ float loadF(const void* p, int i, int f32) {
    if (f32) return ((const float*)p)[i];
    return __bfloat162float(((const __hip_bfloat16*)p)[i]);
}
static __device__ __forceinline__ int loadI(const void* p, int i, int i64) {
    if (i64) return (int)((const long long*)p)[i];
    return ((const int*)p)[i];
}
static __device__ __forceinline__ float bfu2f(unsigned short u) {
    unsigned int t = ((unsigned int)u) << 16;
    float f;
    __builtin_memcpy(&f, &t, 4);
    return f;
}
static __device__ __forceinline__ short f2bf_s(float f) {
    union { __hip_bfloat16 b; short s; } cv;
    cv.b = __float2bfloat16(f);
    return cv.s;
}
static __device__ __forceinline__ unsigned short f2bf_u(float f) {
    union { __hip_bfloat16 b; unsigned short u; } cv;
    cv.b = __float2bfloat16(f);
    return cv.u;
}

// ---- fused prep: [block 0] dtype detect -> flags; [1..64] transpose weights
//      (self-detected float dtype, no flags dependency); [65..260] zero degi ----
__global__ void k_prep(const void* __restrict__ W1, const void* __restrict__ Wmu,
                       const void* __restrict__ Wls, const unsigned short* __restrict__ xs,
                       const int* __restrict__ ei, __hip_bfloat16* __restrict__ Wt1,
                       __hip_bfloat16* __restrict__ Wt2, int* __restrict__ flags,
                       int* __restrict__ degi) {
    int b = blockIdx.x;
    int t = threadIdx.x;
    if (b == 0) {
        __shared__ int cnt[2];
        if (t < 2) cnt[t] = 0;
        __syncthreads();
        unsigned short v = xs[2 * t];
        int e = (v >> 7) & 0xff;
        int sane = (e >= 112 && e <= 133) ? 1 : 0;
        if (v == 0 || v == 0x8000) sane = 1;
        atomicAdd(&cnt[0], sane);
        atomicAdd(&cnt[1], (ei[2 * t + 1] != 0) ? 1 : 0);
        __syncthreads();
        if (t == 0) {
            flags[0] = (cnt[0] < 128) ? 1 : 0;  // few sane bf16 patterns => fp32
            flags[1] = (cnt[1] < 8) ? 1 : 0;    // all-zero odd slots => int64
        }
    } else if (b <= 64) {
        // self-detect float dtype from W1 bit patterns (sigma~0.09 => sane bf16 exps)
        __shared__ int cnt;
        if (t == 0) cnt = 0;
        __syncthreads();
        unsigned short v = ((const unsigned short*)W1)[2 * t];
        int e = (v >> 7) & 0xff;
        atomicAdd(&cnt, (e >= 100 && e <= 133) ? 1 : 0);
        __syncthreads();
        int f32 = (cnt < 128) ? 1 : 0;
        int idx = (b - 1) * 256 + t;  // 16384 total
        int n = idx >> 7, k = idx & 127;
        Wt1[idx] = __float2bfloat16(loadF(W1, k * F + n, f32));
        float v2 = (n < L) ? loadF(Wmu, k * L + n, f32) : loadF(Wls, k * L + (n - L), f32);
        Wt2[idx] = __float2bfloat16(v2);
    } else {
        int i = (b - 65) * 256 + t;
        if (i < N_NODES) degi[i] = 0;
    }
}

// ---- edge prep: convert to int32 src/dst streams + degree counts ----
__global__ void k_eiprep(const void* ei, const int* __restrict__ flags,
                         int* __restrict__ src32, int* __restrict__ dst32,
                         int* __restrict__ degi) {
    int e = blockIdx.x * blockDim.x + threadIdx.x;
    if (e < N_EDGES) {
        int i64 = flags[1];
        int s = loadI(ei, e, i64);
        int d = loadI(ei, N_EDGES + e, i64);
        src32[e] = s;
        dst32[e] = d;
        atomicAdd(&degi[d], 1);
    }
}

// ---- parallel scan phase A: per-block degree sums ----
__global__ void k_bsum(const int* __restrict__ degi, int* __restrict__ bsum) {
    int i = blockIdx.x * 256 + threadIdx.x;
    int v = (i < N_NODES) ? degi[i] : 0;
#pragma unroll
    for (int o = 32; o; o >>= 1) v += __shfl_down(v, o);
    __shared__ int ws[4];
    if ((threadIdx.x & 63) == 0) ws[threadIdx.x >> 6] = v;
    __syncthreads();
    if (threadIdx.x == 0) bsum[blockIdx.x] = ws[0] + ws[1] + ws[2] + ws[3];
}

// ---- parallel scan phase B: exclusive scan of block sums (1 block) ----
__global__ void k_scanb(const int* __restrict__ bsum, int* __restrict__ boff,
                        int* __restrict__ offs) {
    __shared__ int s[256];
    int t = threadIdx.x;
    int v = (t < SCAN_BLOCKS) ? bsum[t] : 0;
    s[t] = v;
    __syncthreads();
    for (int o = 1; o < 256; o <<= 1) {
        int u = (t >= o) ? s[t - o] : 0;
        __syncthreads();
        s[t] += u;
        __syncthreads();
    }
    boff[t] = s[t] - v;  // exclusive
    if (t == 0) offs[N_NODES] = N_EDGES;
}

// ---- phase C: in-block scan + block offset -> offs; also isd and cursor zero ----
__global__ void k_offs(int* __restrict__ degi, const int* __restrict__ boff,
                       int* __restrict__ offs, float* __restrict__ isd) {
    __shared__ int s[256];
    int i = blockIdx.x * 256 + threadIdx.x;
    int t = threadIdx.x;
    int v = (i < N_NODES) ? degi[i] : 0;
    s[t] = v;
    __syncthreads();
    for (int o = 1; o < 256; o <<= 1) {
        int u = (t >= o) ? s[t - o] : 0;
        __syncthreads();
        s[t] += u;
        __syncthreads();
    }
    if (i < N_NODES) {
        offs[i] = boff[blockIdx.x] + s[t] - v;
        isd[i] = 1.0f / sqrtf((float)v + 1.0f);
        degi[i] = 0;  // reuse as fill cursors
    }
}

// ---- XCD-partitioned CSR fill; nt loads keep streams from evicting csr lines ----
__global__ void k_fill(const int* __restrict__ src32, const int* __restrict__ dst32,
                       const int* __restrict__ offs, int* __restrict__ cur,
                       int* __restrict__ csr) {
    int grp = blockIdx.x & (NPART - 1);
    int sub = blockIdx.x >> 3;
    int lo = grp * PART_SZ, hi = lo + PART_SZ;
    int stride = (gridDim.x >> 3) * blockDim.x;
    for (int e = sub * blockDim.x + threadIdx.x; e < N_EDGES; e += stride) {
        int d = __builtin_nontemporal_load(dst32 + e);
        if (d >= lo && d < hi) {
            int pos = offs[d] + atomicAdd(&cur[d], 1);
            csr[pos] = __builtin_nontemporal_load(src32 + e);
        }
    }
}

// ---- MFMA GEMM: outb[N,128](bf16) = Xin[N,128] @ Wt^T, epilogue * isd[row] ----
// mode 0: conv1 — Xin dtype per flags[0], no BN.
// mode 1: conv2 — Xin bf16 h_pre; apply v*bnscale[k]+bnshift[k], relu before MFMA.
__global__ __launch_bounds__(256) void k_gemm_mfma(const void* __restrict__ Xin,
        const __hip_bfloat16* __restrict__ Wt, const float* __restrict__ isd,
        const int* __restrict__ flags, int mode,
        const float* __restrict__ bnscale, const float* __restrict__ bnshift,
        unsigned short* __restrict__ outb) {
    int wave = threadIdx.x >> 6, lane = threadIdx.x & 63;
    int quad = lane >> 4, mr = lane & 15;
    int m0 = blockIdx.x * 64 + wave * 16;
    int row = m0 + mr;
    if (row >= N_NODES) row = N_NODES - 1;
    short8 a[4];
    if (mode == 1) {
        const unsigned short* xb = (const unsigned short*)Xin;
#pragma unroll
        for (int t = 0; t < 4; ++t) {
            int k0 = t * 32 + quad * 8;
            ushort8 raw = *(const ushort8*)(xb + row * F + k0);
            short8 av;
#pragma unroll
            for (int j = 0; j < 8; ++j) {
                float v = bfu2f(raw[j]) * bnscale[k0 + j] + bnshift[k0 + j];
                av[j] = f2bf_s(fmaxf(v, 0.f));
            }
            a[t] = av;
        }
    } else if (flags[0]) {
        const float* xf = (const float*)Xin;
#pragma unroll
        for (int t = 0; t < 4; ++t) {
            int off = row * F + t * 32 + quad * 8;
            short8 av;
#pragma unroll
            for (int j = 0; j < 8; ++j) av[j] = f2bf_s(xf[off + j]);
            a[t] = av;
        }
    } else {
        const short* xb = (const short*)Xin;
#pragma unroll
        for (int t = 0; t < 4; ++t)
            a[t] = *(const short8*)(xb + row * F + t * 32 + quad * 8);
    }
    f32x4 acc[8];
    const short* wb = (const short*)Wt;
#pragma unroll
    for (int nt = 0; nt < 8; ++nt) {
        const short* wp = wb + (nt * 16 + mr) * F + quad * 8;
        f32x4 c = {0.f, 0.f, 0.f, 0.f};
        c = __builtin_amdgcn_mfma_f32_16x16x32_bf16(a[0], *(const short8*)(wp), c, 0, 0, 0);
        c = __builtin_amdgcn_mfma_f32_16x16x32_bf16(a[1], *(const short8*)(wp + 32), c, 0, 0, 0);
        c = __builtin_amdgcn_mfma_f32_16x16x32_bf16(a[2], *(const short8*)(wp + 64), c, 0, 0, 0);
        c = __builtin_amdgcn_mfma_f32_16x16x32_bf16(a[3], *(const short8*)(wp + 96), c, 0, 0, 0);
        acc[nt] = c;
    }
    float sd[4];
    int orow[4];
#pragma unroll
    for (int r = 0; r < 4; ++r) {
        orow[r] = m0 + quad * 4 + r;
        sd[r] = (orow[r] < N_NODES) ? isd[orow[r]] : 0.f;
    }
#pragma unroll
    for (int nt = 0; nt < 8; ++nt)
#pragma unroll
        for (int r = 0; r < 4; ++r)
            if (orow[r] < N_NODES)
                outb[orow[r] * F + nt * 16 + mr] = f2bf_u(acc[nt][r] * sd[r]);
}

// ---- aggregate1: h_pre[d] = isd[d]*(A'[d] + sum A'[s]) + b1 ; bf16 in/out ----
__global__ void k_agg1(const unsigned short* __restrict__ val, const int* __restrict__ csr,
                       const int* __restrict__ offs, const float* __restrict__ isd,
                       const void* __restrict__ b1, const int* __restrict__ flags,
                       unsigned short* __restrict__ out) {
    int node = blockIdx.x * 4 + (threadIdx.x >> 6);
    if (node >= N_NODES) return;
    int lane = threadIdx.x & 63;
    int grp = lane >> 4, l16 = lane & 15;
    const ushort8* vp = (const ushort8*)val;
    float acc[8] = {0.f, 0.f, 0.f, 0.f, 0.f, 0.f, 0.f, 0.f};
    if (grp == 0) {
        ushort8 u = vp[node * 16 + l16];  // self loop
#pragma unroll
        for (int j = 0; j < 8; ++j) acc[j] = bfu2f(u[j]);
    }
    int end = offs[node + 1];
    int i = offs[node] + grp;
    for (; i + 4 < end; i += 8) {
        int s0 = __builtin_nontemporal_load(csr + i);
        int s1 = __builtin_nontemporal_load(csr + i + 4);
        ushort8 u0 = vp[s0 * 16 + l16];
        ushort8 u1 = vp[s1 * 16 + l16];
#pragma unroll
        for (int j = 0; j < 8; ++j) acc[j] += bfu2f(u0[j]) + bfu2f(u1[j]);
    }
    for (; i < end; i += 4) {
        int s0 = __builtin_nontemporal_load(csr + i);
        ushort8 u = vp[s0 * 16 + l16];
#pragma unroll
        for (int j = 0; j < 8; ++j) acc[j] += bfu2f(u[j]);
    }
#pragma unroll
    for (int j = 0; j < 8; ++j) {
        acc[j] += __shfl_xor(acc[j], 16);
        acc[j] += __shfl_xor(acc[j], 32);
    }
    if (grp == 0) {
        float sd = isd[node];
        int c0 = l16 * 8, f32 = flags[0];
        ushort8 r;
#pragma unroll
        for (int j = 0; j < 8; ++j) r[j] = f2bf_u(acc[j] * sd + loadF(b1, c0 + j, f32));
        ((ushort8*)out)[node * 16 + l16] = r;
    }
}

// ---- BN stats phase 1: per-block column sums / sum-of-squares (no atomics) ----
__global__ void k_bnstats(const unsigned short* __restrict__ h, float* __restrict__ partial) {
    __shared__ float ls[256][8];
    __shared__ float lq[256][8];
    int t = threadIdx.x;
    int o = t & 15, rg = t >> 4;
    int row0 = blockIdx.x * 128 + rg;
    float s[8] = {0.f}, q[8] = {0.f};
#pragma unroll
    for (int i = 0; i < 8; ++i) {
        int row = row0 + i * 16;
        if (row < N_NODES) {
            ushort8 u = *(const ushort8*)(h + row * F + o * 8);
#pragma unroll
            for (int j = 0; j < 8; ++j) {
                float v = bfu2f(u[j]);
                s[j] += v;
                q[j] += v * v;
            }
        }
    }
#pragma unroll
    for (int j = 0; j < 8; ++j) { ls[t][j] = s[j]; lq[t][j] = q[j]; }
    __syncthreads();
    if (t < 128) {
        int c = t, oo = c >> 3, jj = c & 7;
        float ts = 0.f, tq = 0.f;
#pragma unroll
        for (int rgi = 0; rgi < 16; ++rgi) {
            ts += ls[rgi * 16 + oo][jj];
            tq += lq[rgi * 16 + oo][jj];
        }
        partial[blockIdx.x * 256 + c] = ts;
        partial[blockIdx.x * 256 + 128 + c] = tq;
    }
}

// ---- fused BN reduce + coefficient prep: block c -> scale[c], shift[c] ----
__global__ void k_bnredprep(const float* __restrict__ partial, const void* __restrict__ gamma,
                            const void* __restrict__ beta, const int* __restrict__ flags,
                            float* __restrict__ scale, float* __restrict__ shift) {
    int c = blockIdx.x;  // 0..127
    float s = 0.f, q = 0.f;
    for (int b = threadIdx.x; b < BN_BLOCKS; b += 256) {
        s += partial[b * 256 + c];
        q += partial[b * 256 + 128 + c];
    }
#pragma unroll
    for (int o = 32; o; o >>= 1) {
        s += __shfl_down(s, o);
        q += __shfl_down(q, o);
    }
    __shared__ float ws[4], wq[4];
    if ((threadIdx.x & 63) == 0) {
        ws[threadIdx.x >> 6] = s;
        wq[threadIdx.x >> 6] = q;
    }
    __syncthreads();
    if (threadIdx.x == 0) {
        float S = ws[0] + ws[1] + ws[2] + ws[3];
        float Q = wq[0] + wq[1] + wq[2] + wq[3];
        const float invN = 1.0f / (float)N_NODES;
        float m = S * invN;
        float var = Q * invN - m * m;
        int f32 = flags[0];
        float sc = loadF(gamma, c, f32) * rsqrtf(var + BN_EPS);
        scale[c] = sc;
        shift[c] = loadF(beta, c, f32) - m * sc;
    }
}

// ---- aggregate2 + epilogue: write mu[N,64] ++ log_std[N,64] in output dtype ----
__global__ void k_agg2(const unsigned short* __restrict__ val, const int* __restrict__ csr,
                       const int* __restrict__ offs, const float* __restrict__ isd,
                       const void* __restrict__ bmu, const void* __restrict__ bls,
                       const int* __restrict__ flags, void* __restrict__ out) {
    int node = blockIdx.x * 4 + (threadIdx.x >> 6);
    if (node >= N_NODES) return;
    int lane = threadIdx.x & 63;
    int grp = lane >> 4, l16 = lane & 15;
    const ushort8* vp = (const ushort8*)val;
    float acc[8] = {0.f, 0.f, 0.f, 0.f, 0.f, 0.f, 0.f, 0.f};
    if (grp == 0) {
        ushort8 u = vp[node * 16 + l16];  // self loop
#pragma unroll
        for (int j = 0; j < 8; ++j) acc[j] = bfu2f(u[j]);
    }
    int end = offs[node + 1];
    int i = offs[node] + grp;
    for (; i + 4 < end; i += 8) {
        int s0 = __builtin_nontemporal_load(csr + i);
        int s1 = __builtin_nontemporal_load(csr + i + 4);
        ushort8 u0 = vp[s0 * 16 + l16];
        ushort8 u1 = vp[s1 * 16 + l16];
#pragma unroll
        for (int j = 0; j < 8; ++j) acc[j] += bfu2f(u0[j]) + bfu2f(u1[j]);
    }
    for (; i < end; i += 4) {
        int s0 = __builtin_nontemporal_load(csr + i);
        ushort8 u = vp[s0 * 16 + l16];
#pragma unroll
        for (int j = 0; j < 8; ++j) acc[j] += bfu2f(u[j]);
    }
#pragma unroll
    for (int j = 0; j < 8; ++j) {
        acc[j] += __shfl_xor(acc[j], 16);
        acc[j] += __shfl_xor(acc[j], 32);
    }
    if (grp == 0) {
        float sd = isd[node];
        int c0 = l16 * 8, f32 = flags[0];
        int hsel = (c0 >= L) ? 1 : 0;
        int cc = c0 - hsel * L;
        const void* bp = hsel ? bls : bmu;
        float o8[8];
#pragma unroll
        for (int j = 0; j < 8; ++j) o8[j] = acc[j] * sd + loadF(bp, cc + j, f32);
        long base_o = (long)hsel * (N_NODES * 64) + (long)node * 64 + cc;
        if (f32) {
            float4 r0 = make_float4(o8[0], o8[1], o8[2], o8[3]);
            float4 r1 = make_float4(o8[4], o8[5], o8[6], o8[7]);
            *(float4*)((float*)out + base_o) = r0;
            *(float4*)((float*)out + base_o + 4) = r1;
        } else {
            ushort8 r;
#pragma unroll
            for (int j = 0; j < 8; ++j) r[j] = f2bf_u(o8[j]);
            *(ushort8*)((__hip_bfloat16*)out + base_o) = r;
        }
    }
}

extern "C" void kernel_launch(void* const* d_in, const int* in_sizes, int n_in,
                              void* d_out, int out_size, void* d_ws, size_t ws_size,
                              hipStream_t stream) {
    const void* x     = d_in[0];
    const void* ei    = d_in[1];
    const void* W1    = d_in[2];
    const void* b1    = d_in[3];
    const void* gamma = d_in[4];
    const void* beta  = d_in[5];
    const void* Wmu   = d_in[6];
    const void* bmu   = d_in[7];
    const void* Wls   = d_in[8];
    const void* bls   = d_in[9];

    int*   degi  = (int*)d_ws;                     // [50048] deg counts -> fill cursors
    int*   offs  = degi + 50048;                   // [50048]
    float* isd   = (float*)(offs + 50048);         // [50000]
    float* stats = isd + 50000;                    // scale[128] shift[128] (+pad)
    int*   flags = (int*)(stats + 512);            // [16]
    int*   bsum  = flags + 16;                     // [256]
    int*   boff  = bsum + 256;                     // [256]
    int*   csr   = boff + 256;                     // [800000]
    int*   src32 = csr + 800000;                   // [800000]
    int*   dst32 = src32 + 800000;                 // [800000]
    __hip_bfloat16* Wt1 = (__hip_bfloat16*)(dst32 + 800000); // [16384]
    __hip_bfloat16* Wt2 = Wt1 + 16384;                       // [16384]
    unsigned short* Abf = (unsigned short*)(Wt2 + 16384);    // [N*128] bf16 A'
    unsigned short* Hpre = Abf + N_NODES * F;                // [N*128] bf16 h_pre
    float* partial = (float*)(Hpre + N_NODES * F);           // [BN_BLOCKS*256]

    const int NT = 256;
    const int AGG_BLOCKS = (N_NODES + 3) / 4;
    const int GEMM_BLOCKS = (N_NODES + 63) / 64;

    // prep: detect + weight transpose + degi zero (one kernel)
    k_prep<<<65 + SCAN_BLOCKS, NT, 0, stream>>>(W1, Wmu, Wls, (const unsigned short*)x,
                                                (const int*)ei, Wt1, Wt2, flags, degi);
    k_eiprep<<<(N_EDGES + NT - 1) / NT, NT, 0, stream>>>(ei, flags, src32, dst32, degi);
    k_bsum<<<SCAN_BLOCKS, NT, 0, stream>>>(degi, bsum);
    k_scanb<<<1, NT, 0, stream>>>(bsum, boff, offs);
    k_offs<<<SCAN_BLOCKS, NT, 0, stream>>>(degi, boff, offs, isd);  // + isd + cursor zero
    k_fill<<<512, NT, 0, stream>>>(src32, dst32, offs, degi, csr);  // 8 XCD groups x 64

    // conv1: A'1 = (x @ W1)*isd  -> bf16
    k_gemm_mfma<<<GEMM_BLOCKS, NT, 0, stream>>>(x, Wt1, isd, flags, 0, nullptr, nullptr, Abf);
    k_agg1<<<AGG_BLOCKS, NT, 0, stream>>>(Abf, csr, offs, isd, b1, flags, Hpre);

    // batchnorm stats (2-phase, no atomics) + fused reduce/prep
    k_bnstats<<<BN_BLOCKS, NT, 0, stream>>>(Hpre, partial);
    k_bnredprep<<<128, NT, 0, stream>>>(partial, gamma, beta, flags, stats, stats + 128);

    // conv2: A'2 = (relu(bn(h_pre)) @ [Wmu|Wls])*isd -> bf16 (reuses Abf)
    k_gemm_mfma<<<GEMM_BLOCKS, NT, 0, stream>>>(Hpre, Wt2, isd, flags, 1,
                                                stats, stats + 128, Abf);
    k_agg2<<<AGG_BLOCKS, NT, 0, stream>>>(Abf, csr, offs, isd, bmu, bls, flags, d_out);
}

// Round 10
// 315.433 us; speedup vs baseline: 1.1044x; 1.1044x over previous
//
#include <hip/hip_runtime.h>
#include <hip/hip_bf16.h>

#define N_NODES 50000
#define N_EDGES 800000
#define F 128
#define L 64
#define BN_EPS 1e-5f
#define SCAN_BLOCKS 196   // ceil(50000/256)
#define BN_BLOCKS 391     // ceil(50000/128)
#define NPART 8
#define PART_SZ 6250      // 50000/8
#define FILL_BLOCKS 2048  // 8 XCD groups x 256 sub-blocks -> 8 blocks/CU

typedef __attribute__((ext_vector_type(8))) short short8;
typedef __attribute__((ext_vector_type(8))) unsigned short ushort8;
typedef __attribute__((ext_vector_type(4))) float f32x4;

// ---------------- runtime dtype adaptivity ----------------
// flags[0] = 1 if float inputs are fp32, 0 if bf16
// flags[1] = 1 if edge_index is int64, 0 if int32
static __device__ __forceinline__ float loadF(const void* p, int i, int f32) {
    if (f32) return ((const float*)p)[i];
    return __bfloat162float(((const __hip_bfloat16*)p)[i]);
}
static __device__ __forceinline__ int loadI(const void* p, int i, int i64) {
    if (i64) return (int)((const long long*)p)[i];
    return ((const int*)p)[i];
}
static __device__ __forceinline__ float bfu2f(unsigned short u) {
    unsigned int t = ((unsigned int)u) << 16;
    float f;
    __builtin_memcpy(&f, &t, 4);
    return f;
}
static __device__ __forceinline__ short f2bf_s(float f) {
    union { __hip_bfloat16 b; short s; } cv;
    cv.b = __float2bfloat16(f);
    return cv.s;
}
static __device__ __forceinline__ unsigned short f2bf_u(float f) {
    union { __hip_bfloat16 b; unsigned short u; } cv;
    cv.b = __float2bfloat16(f);
    return cv.u;
}

// ---- fused prep: [block 0] dtype detect -> flags; [1..64] transpose weights
//      (self-detected float dtype, no flags dependency); [65..260] zero degi ----
__global__ void k_prep(const void* __restrict__ W1, const void* __restrict__ Wmu,
                       const void* __restrict__ Wls, const unsigned short* __restrict__ xs,
                       const int* __restrict__ ei, __hip_bfloat16* __restrict__ Wt1,
                       __hip_bfloat16* __restrict__ Wt2, int* __restrict__ flags,
                       int* __restrict__ degi) {
    int b = blockIdx.x;
    int t = threadIdx.x;
    if (b == 0) {
        __shared__ int cnt[2];
        if (t < 2) cnt[t] = 0;
        __syncthreads();
        unsigned short v = xs[2 * t];
        int e = (v >> 7) & 0xff;
        int sane = (e >= 112 && e <= 133) ? 1 : 0;
        if (v == 0 || v == 0x8000) sane = 1;
        atomicAdd(&cnt[0], sane);
        atomicAdd(&cnt[1], (ei[2 * t + 1] != 0) ? 1 : 0);
        __syncthreads();
        if (t == 0) {
            flags[0] = (cnt[0] < 128) ? 1 : 0;  // few sane bf16 patterns => fp32
            flags[1] = (cnt[1] < 8) ? 1 : 0;    // all-zero odd slots => int64
        }
    } else if (b <= 64) {
        // self-detect float dtype from W1 bit patterns (sigma~0.09 => sane bf16 exps)
        __shared__ int cnt;
        if (t == 0) cnt = 0;
        __syncthreads();
        unsigned short v = ((const unsigned short*)W1)[2 * t];
        int e = (v >> 7) & 0xff;
        atomicAdd(&cnt, (e >= 100 && e <= 133) ? 1 : 0);
        __syncthreads();
        int f32 = (cnt < 128) ? 1 : 0;
        int idx = (b - 1) * 256 + t;  // 16384 total
        int n = idx >> 7, k = idx & 127;
        Wt1[idx] = __float2bfloat16(loadF(W1, k * F + n, f32));
        float v2 = (n < L) ? loadF(Wmu, k * L + n, f32) : loadF(Wls, k * L + (n - L), f32);
        Wt2[idx] = __float2bfloat16(v2);
    } else {
        int i = (b - 65) * 256 + t;
        if (i < N_NODES) degi[i] = 0;
    }
}

// ---- edge prep: degree counts; int64 case also converts to int32 streams ----
__global__ void k_eiprep(const void* ei, const int* __restrict__ flags,
                         int* __restrict__ src32, int* __restrict__ dst32,
                         int* __restrict__ degi) {
    int e = blockIdx.x * blockDim.x + threadIdx.x;
    if (e < N_EDGES) {
        int i64 = flags[1];
        int d = loadI(ei, N_EDGES + e, i64);
        if (i64) {
            src32[e] = loadI(ei, e, 1);
            dst32[e] = d;
        }
        atomicAdd(&degi[d], 1);
    }
}

// ---- parallel scan phase A: per-block degree sums ----
__global__ void k_bsum(const int* __restrict__ degi, int* __restrict__ bsum) {
    int i = blockIdx.x * 256 + threadIdx.x;
    int v = (i < N_NODES) ? degi[i] : 0;
#pragma unroll
    for (int o = 32; o; o >>= 1) v += __shfl_down(v, o);
    __shared__ int ws[4];
    if ((threadIdx.x & 63) == 0) ws[threadIdx.x >> 6] = v;
    __syncthreads();
    if (threadIdx.x == 0) bsum[blockIdx.x] = ws[0] + ws[1] + ws[2] + ws[3];
}

// ---- parallel scan phase B: exclusive scan of block sums (1 block) ----
__global__ void k_scanb(const int* __restrict__ bsum, int* __restrict__ boff,
                        int* __restrict__ offs) {
    __shared__ int s[256];
    int t = threadIdx.x;
    int v = (t < SCAN_BLOCKS) ? bsum[t] : 0;
    s[t] = v;
    __syncthreads();
    for (int o = 1; o < 256; o <<= 1) {
        int u = (t >= o) ? s[t - o] : 0;
        __syncthreads();
        s[t] += u;
        __syncthreads();
    }
    boff[t] = s[t] - v;  // exclusive
    if (t == 0) offs[N_NODES] = N_EDGES;
}

// ---- phase C: in-block scan + block offset -> offs; also isd and cursor zero ----
__global__ void k_offs(int* __restrict__ degi, const int* __restrict__ boff,
                       int* __restrict__ offs, float* __restrict__ isd) {
    __shared__ int s[256];
    int i = blockIdx.x * 256 + threadIdx.x;
    int t = threadIdx.x;
    int v = (i < N_NODES) ? degi[i] : 0;
    s[t] = v;
    __syncthreads();
    for (int o = 1; o < 256; o <<= 1) {
        int u = (t >= o) ? s[t - o] : 0;
        __syncthreads();
        s[t] += u;
        __syncthreads();
    }
    if (i < N_NODES) {
        offs[i] = boff[blockIdx.x] + s[t] - v;
        isd[i] = 1.0f / sqrtf((float)v + 1.0f);
        degi[i] = 0;  // reuse as fill cursors
    }
}

// ---- XCD-partitioned CSR fill (high occupancy for atomic-chain latency hiding) ----
// group g = blockIdx%8 handles dst in [g*6250, (g+1)*6250); src/dst stream
// selected per flags[1]: int32 -> read ei directly, int64 -> converted copies.
__global__ void k_fill(const int* __restrict__ ei32, const int* __restrict__ src32,
                       const int* __restrict__ dst32, const int* __restrict__ flags,
                       const int* __restrict__ offs, int* __restrict__ cur,
                       int* __restrict__ csr) {
    const int* sp;
    const int* dp;
    if (flags[1]) { sp = src32; dp = dst32; }
    else          { sp = ei32;  dp = ei32 + N_EDGES; }
    int grp = blockIdx.x & (NPART - 1);
    int sub = blockIdx.x >> 3;
    int lo = grp * PART_SZ, hi = lo + PART_SZ;
    int stride = (FILL_BLOCKS >> 3) * 256;
    for (int e = sub * 256 + threadIdx.x; e < N_EDGES; e += stride) {
        int d = dp[e];
        if (d >= lo && d < hi) {
            int pos = offs[d] + atomicAdd(&cur[d], 1);
            csr[pos] = sp[e];
        }
    }
}

// ---- MFMA GEMM: outb[N,128](bf16) = Xin[N,128] @ Wt^T, epilogue * isd[row] ----
// mode 0: conv1 — Xin dtype per flags[0], no BN.
// mode 1: conv2 — Xin bf16 h_pre; apply v*bnscale[k]+bnshift[k], relu before MFMA.
__global__ __launch_bounds__(256) void k_gemm_mfma(const void* __restrict__ Xin,
        const __hip_bfloat16* __restrict__ Wt, const float* __restrict__ isd,
        const int* __restrict__ flags, int mode,
        const float* __restrict__ bnscale, const float* __restrict__ bnshift,
        unsigned short* __restrict__ outb) {
    int wave = threadIdx.x >> 6, lane = threadIdx.x & 63;
    int quad = lane >> 4, mr = lane & 15;
    int m0 = blockIdx.x * 64 + wave * 16;
    int row = m0 + mr;
    if (row >= N_NODES) row = N_NODES - 1;
    short8 a[4];
    if (mode == 1) {
        const unsigned short* xb = (const unsigned short*)Xin;
#pragma unroll
        for (int t = 0; t < 4; ++t) {
            int k0 = t * 32 + quad * 8;
            ushort8 raw = *(const ushort8*)(xb + row * F + k0);
            short8 av;
#pragma unroll
            for (int j = 0; j < 8; ++j) {
                float v = bfu2f(raw[j]) * bnscale[k0 + j] + bnshift[k0 + j];
                av[j] = f2bf_s(fmaxf(v, 0.f));
            }
            a[t] = av;
        }
    } else if (flags[0]) {
        const float* xf = (const float*)Xin;
#pragma unroll
        for (int t = 0; t < 4; ++t) {
            int off = row * F + t * 32 + quad * 8;
            short8 av;
#pragma unroll
            for (int j = 0; j < 8; ++j) av[j] = f2bf_s(xf[off + j]);
            a[t] = av;
        }
    } else {
        const short* xb = (const short*)Xin;
#pragma unroll
        for (int t = 0; t < 4; ++t)
            a[t] = *(const short8*)(xb + row * F + t * 32 + quad * 8);
    }
    f32x4 acc[8];
    const short* wb = (const short*)Wt;
#pragma unroll
    for (int nt = 0; nt < 8; ++nt) {
        const short* wp = wb + (nt * 16 + mr) * F + quad * 8;
        f32x4 c = {0.f, 0.f, 0.f, 0.f};
        c = __builtin_amdgcn_mfma_f32_16x16x32_bf16(a[0], *(const short8*)(wp), c, 0, 0, 0);
        c = __builtin_amdgcn_mfma_f32_16x16x32_bf16(a[1], *(const short8*)(wp + 32), c, 0, 0, 0);
        c = __builtin_amdgcn_mfma_f32_16x16x32_bf16(a[2], *(const short8*)(wp + 64), c, 0, 0, 0);
        c = __builtin_amdgcn_mfma_f32_16x16x32_bf16(a[3], *(const short8*)(wp + 96), c, 0, 0, 0);
        acc[nt] = c;
    }
    float sd[4];
    int orow[4];
#pragma unroll
    for (int r = 0; r < 4; ++r) {
        orow[r] = m0 + quad * 4 + r;
        sd[r] = (orow[r] < N_NODES) ? isd[orow[r]] : 0.f;
    }
#pragma unroll
    for (int nt = 0; nt < 8; ++nt)
#pragma unroll
        for (int r = 0; r < 4; ++r)
            if (orow[r] < N_NODES)
                outb[orow[r] * F + nt * 16 + mr] = f2bf_u(acc[nt][r] * sd[r]);
}

// ---- aggregate1: h_pre[d] = isd[d]*(A'[d] + sum A'[s]) + b1 ; bf16 in/out ----
__global__ void k_agg1(const unsigned short* __restrict__ val, const int* __restrict__ csr,
                       const int* __restrict__ offs, const float* __restrict__ isd,
                       const void* __restrict__ b1, const int* __restrict__ flags,
                       unsigned short* __restrict__ out) {
    int node = blockIdx.x * 4 + (threadIdx.x >> 6);
    if (node >= N_NODES) return;
    int lane = threadIdx.x & 63;
    int grp = lane >> 4, l16 = lane & 15;
    const ushort8* vp = (const ushort8*)val;
    float acc[8] = {0.f, 0.f, 0.f, 0.f, 0.f, 0.f, 0.f, 0.f};
    if (grp == 0) {
        ushort8 u = vp[node * 16 + l16];  // self loop
#pragma unroll
        for (int j = 0; j < 8; ++j) acc[j] = bfu2f(u[j]);
    }
    int end = offs[node + 1];
    int i = offs[node] + grp;
    for (; i + 4 < end; i += 8) {
        ushort8 u0 = vp[csr[i] * 16 + l16];
        ushort8 u1 = vp[csr[i + 4] * 16 + l16];
#pragma unroll
        for (int j = 0; j < 8; ++j) acc[j] += bfu2f(u0[j]) + bfu2f(u1[j]);
    }
    for (; i < end; i += 4) {
        ushort8 u = vp[csr[i] * 16 + l16];
#pragma unroll
        for (int j = 0; j < 8; ++j) acc[j] += bfu2f(u[j]);
    }
#pragma unroll
    for (int j = 0; j < 8; ++j) {
        acc[j] += __shfl_xor(acc[j], 16);
        acc[j] += __shfl_xor(acc[j], 32);
    }
    if (grp == 0) {
        float sd = isd[node];
        int c0 = l16 * 8, f32 = flags[0];
        ushort8 r;
#pragma unroll
        for (int j = 0; j < 8; ++j) r[j] = f2bf_u(acc[j] * sd + loadF(b1, c0 + j, f32));
        ((ushort8*)out)[node * 16 + l16] = r;
    }
}

// ---- BN stats phase 1: per-block column sums / sum-of-squares (no atomics) ----
__global__ void k_bnstats(const unsigned short* __restrict__ h, float* __restrict__ partial) {
    __shared__ float ls[256][8];
    __shared__ float lq[256][8];
    int t = threadIdx.x;
    int o = t & 15, rg = t >> 4;
    int row0 = blockIdx.x * 128 + rg;
    float s[8] = {0.f}, q[8] = {0.f};
#pragma unroll
    for (int i = 0; i < 8; ++i) {
        int row = row0 + i * 16;
        if (row < N_NODES) {
            ushort8 u = *(const ushort8*)(h + row * F + o * 8);
#pragma unroll
            for (int j = 0; j < 8; ++j) {
                float v = bfu2f(u[j]);
                s[j] += v;
                q[j] += v * v;
            }
        }
    }
#pragma unroll
    for (int j = 0; j < 8; ++j) { ls[t][j] = s[j]; lq[t][j] = q[j]; }
    __syncthreads();
    if (t < 128) {
        int c = t, oo = c >> 3, jj = c & 7;
        float ts = 0.f, tq = 0.f;
#pragma unroll
        for (int rgi = 0; rgi < 16; ++rgi) {
            ts += ls[rgi * 16 + oo][jj];
            tq += lq[rgi * 16 + oo][jj];
        }
        partial[blockIdx.x * 256 + c] = ts;
        partial[blockIdx.x * 256 + 128 + c] = tq;
    }
}

// ---- fused BN reduce + coefficient prep: block c -> scale[c], shift[c] ----
__global__ void k_bnredprep(const float* __restrict__ partial, const void* __restrict__ gamma,
                            const void* __restrict__ beta, const int* __restrict__ flags,
                            float* __restrict__ scale, float* __restrict__ shift) {
    int c = blockIdx.x;  // 0..127
    float s = 0.f, q = 0.f;
    for (int b = threadIdx.x; b < BN_BLOCKS; b += 256) {
        s += partial[b * 256 + c];
        q += partial[b * 256 + 128 + c];
    }
#pragma unroll
    for (int o = 32; o; o >>= 1) {
        s += __shfl_down(s, o);
        q += __shfl_down(q, o);
    }
    __shared__ float ws[4], wq[4];
    if ((threadIdx.x & 63) == 0) {
        ws[threadIdx.x >> 6] = s;
        wq[threadIdx.x >> 6] = q;
    }
    __syncthreads();
    if (threadIdx.x == 0) {
        float S = ws[0] + ws[1] + ws[2] + ws[3];
        float Q = wq[0] + wq[1] + wq[2] + wq[3];
        const float invN = 1.0f / (float)N_NODES;
        float m = S * invN;
        float var = Q * invN - m * m;
        int f32 = flags[0];
        float sc = loadF(gamma, c, f32) * rsqrtf(var + BN_EPS);
        scale[c] = sc;
        shift[c] = loadF(beta, c, f32) - m * sc;
    }
}

// ---- aggregate2 + epilogue: write mu[N,64] ++ log_std[N,64] in output dtype ----
__global__ void k_agg2(const unsigned short* __restrict__ val, const int* __restrict__ csr,
                       const int* __restrict__ offs, const float* __restrict__ isd,
                       const void* __restrict__ bmu, const void* __restrict__ bls,
                       const int* __restrict__ flags, void* __restrict__ out) {
    int node = blockIdx.x * 4 + (threadIdx.x >> 6);
    if (node >= N_NODES) return;
    int lane = threadIdx.x & 63;
    int grp = lane >> 4, l16 = lane & 15;
    const ushort8* vp = (const ushort8*)val;
    float acc[8] = {0.f, 0.f, 0.f, 0.f, 0.f, 0.f, 0.f, 0.f};
    if (grp == 0) {
        ushort8 u = vp[node * 16 + l16];  // self loop
#pragma unroll
        for (int j = 0; j < 8; ++j) acc[j] = bfu2f(u[j]);
    }
    int end = offs[node + 1];
    int i = offs[node] + grp;
    for (; i + 4 < end; i += 8) {
        ushort8 u0 = vp[csr[i] * 16 + l16];
        ushort8 u1 = vp[csr[i + 4] * 16 + l16];
#pragma unroll
        for (int j = 0; j < 8; ++j) acc[j] += bfu2f(u0[j]) + bfu2f(u1[j]);
    }
    for (; i < end; i += 4) {
        ushort8 u = vp[csr[i] * 16 + l16];
#pragma unroll
        for (int j = 0; j < 8; ++j) acc[j] += bfu2f(u[j]);
    }
#pragma unroll
    for (int j = 0; j < 8; ++j) {
        acc[j] += __shfl_xor(acc[j], 16);
        acc[j] += __shfl_xor(acc[j], 32);
    }
    if (grp == 0) {
        float sd = isd[node];
        int c0 = l16 * 8, f32 = flags[0];
        int hsel = (c0 >= L) ? 1 : 0;
        int cc = c0 - hsel * L;
        const void* bp = hsel ? bls : bmu;
        float o8[8];
#pragma unroll
        for (int j = 0; j < 8; ++j) o8[j] = acc[j] * sd + loadF(bp, cc + j, f32);
        long base_o = (long)hsel * (N_NODES * 64) + (long)node * 64 + cc;
        if (f32) {
            float4 r0 = make_float4(o8[0], o8[1], o8[2], o8[3]);
            float4 r1 = make_float4(o8[4], o8[5], o8[6], o8[7]);
            *(float4*)((float*)out + base_o) = r0;
            *(float4*)((float*)out + base_o + 4) = r1;
        } else {
            ushort8 r;
#pragma unroll
            for (int j = 0; j < 8; ++j) r[j] = f2bf_u(o8[j]);
            *(ushort8*)((__hip_bfloat16*)out + base_o) = r;
        }
    }
}

extern "C" void kernel_launch(void* const* d_in, const int* in_sizes, int n_in,
                              void* d_out, int out_size, void* d_ws, size_t ws_size,
                              hipStream_t stream) {
    const void* x     = d_in[0];
    const void* ei    = d_in[1];
    const void* W1    = d_in[2];
    const void* b1    = d_in[3];
    const void* gamma = d_in[4];
    const void* beta  = d_in[5];
    const void* Wmu   = d_in[6];
    const void* bmu   = d_in[7];
    const void* Wls   = d_in[8];
    const void* bls   = d_in[9];

    int*   degi  = (int*)d_ws;                     // [50048] deg counts -> fill cursors
    int*   offs  = degi + 50048;                   // [50048]
    float* isd   = (float*)(offs + 50048);         // [50000]
    float* stats = isd + 50000;                    // scale[128] shift[128] (+pad)
    int*   flags = (int*)(stats + 512);            // [16]
    int*   bsum  = flags + 16;                     // [256]
    int*   boff  = bsum + 256;                     // [256]
    int*   csr   = boff + 256;                     // [800000]
    int*   src32 = csr + 800000;                   // [800000] (int64 case only)
    int*   dst32 = src32 + 800000;                 // [800000] (int64 case only)
    __hip_bfloat16* Wt1 = (__hip_bfloat16*)(dst32 + 800000); // [16384]
    __hip_bfloat16* Wt2 = Wt1 + 16384;                       // [16384]
    unsigned short* Abf = (unsigned short*)(Wt2 + 16384);    // [N*128] bf16 A'
    unsigned short* Hpre = Abf + N_NODES * F;                // [N*128] bf16 h_pre
    float* partial = (float*)(Hpre + N_NODES * F);           // [BN_BLOCKS*256]

    const int NT = 256;
    const int AGG_BLOCKS = (N_NODES + 3) / 4;
    const int GEMM_BLOCKS = (N_NODES + 63) / 64;

    // prep: detect + weight transpose + degi zero (one kernel)
    k_prep<<<65 + SCAN_BLOCKS, NT, 0, stream>>>(W1, Wmu, Wls, (const unsigned short*)x,
                                                (const int*)ei, Wt1, Wt2, flags, degi);
    k_eiprep<<<(N_EDGES + NT - 1) / NT, NT, 0, stream>>>(ei, flags, src32, dst32, degi);
    k_bsum<<<SCAN_BLOCKS, NT, 0, stream>>>(degi, bsum);
    k_scanb<<<1, NT, 0, stream>>>(bsum, boff, offs);
    k_offs<<<SCAN_BLOCKS, NT, 0, stream>>>(degi, boff, offs, isd);  // + isd + cursor zero
    k_fill<<<FILL_BLOCKS, NT, 0, stream>>>((const int*)ei, src32, dst32, flags,
                                           offs, degi, csr);

    // conv1: A'1 = (x @ W1)*isd  -> bf16
    k_gemm_mfma<<<GEMM_BLOCKS, NT, 0, stream>>>(x, Wt1, isd, flags, 0, nullptr, nullptr, Abf);
    k_agg1<<<AGG_BLOCKS, NT, 0, stream>>>(Abf, csr, offs, isd, b1, flags, Hpre);

    // batchnorm stats (2-phase, no atomics) + fused reduce/prep
    k_bnstats<<<BN_BLOCKS, NT, 0, stream>>>(Hpre, partial);
    k_bnredprep<<<128, NT, 0, stream>>>(partial, gamma, beta, flags, stats, stats + 128);

    // conv2: A'2 = (relu(bn(h_pre)) @ [Wmu|Wls])*isd -> bf16 (reuses Abf)
    k_gemm_mfma<<<GEMM_BLOCKS, NT, 0, stream>>>(Hpre, Wt2, isd, flags, 1,
                                                stats, stats + 128, Abf);
    k_agg2<<<AGG_BLOCKS, NT, 0, stream>>>(Abf, csr, offs, isd, bmu, bls, flags, d_out);
}